// Round 1
// baseline (1836.849 us; speedup 1.0000x reference)
//
#include <hip/hip_runtime.h>
#include <cstddef>

#define B_ 32
#define T_ 1024
#define IN_ 256
#define H_ 512
#define O_ 256
#define DT_ 0.1f

typedef _Float16 half2_t __attribute__((ext_vector_type(2)));

__device__ __forceinline__ float fdot2(half2_t a, half2_t b, float c) {
#if defined(__has_builtin)
#if __has_builtin(__builtin_amdgcn_fdot2)
    return __builtin_amdgcn_fdot2(a, b, c, false);
#else
    return c + (float)a[0] * (float)b[0] + (float)a[1] * (float)b[1];
#endif
#else
    return c + (float)a[0] * (float)b[0] + (float)a[1] * (float)b[1];
#endif
}

__device__ __forceinline__ half2_t cvt2(float x, float y) {
    half2_t r; r[0] = (_Float16)x; r[1] = (_Float16)y; return r;
}

__device__ __forceinline__ half2_t as_h2(float f) {
    union { float f; half2_t h; } u; u.f = f; return u.h;
}

// ---------------------------------------------------------------------------
// Generic fp32 GEMM: C[m][n] = sum_k A[m][k] * Bw[n][k],  M = 32768 fixed.
// Row index m = t*32 + b.  SWA/SWC remap the A/C row to (b*T + t) layout.
// 128x128 tile, kc=32, 256 threads, 8x8 micro-tile per thread.
// ---------------------------------------------------------------------------
template<int N, int K, bool SWA, bool SWC>
__global__ __launch_bounds__(256, 4) void gemm128(const float* __restrict__ A,
                                                  const float* __restrict__ Bw,
                                                  float* __restrict__ C) {
    __shared__ float al[32][132];
    __shared__ float bl[32][132];
    const int tid = threadIdx.x;
    const int m0 = blockIdx.x * 128;
    const int n0 = blockIdx.y * 128;
    const int tx = tid & 15;
    const int ty = tid >> 4;
    float acc[8][8] = {};

    const int lrow = tid >> 3;
    const int kk = (tid & 7) * 4;

    for (int kc = 0; kc < K; kc += 32) {
        __syncthreads();
#pragma unroll
        for (int p = 0; p < 4; ++p) {
            const int row = lrow + p * 32;
            const int m = m0 + row;
            const size_t aoff = SWA ? ((size_t)((m & 31) * T_ + (m >> 5)) * K)
                                    : ((size_t)m * K);
            const float4 v = *(const float4*)(A + aoff + kc + kk);
            al[kk + 0][row] = v.x; al[kk + 1][row] = v.y;
            al[kk + 2][row] = v.z; al[kk + 3][row] = v.w;
        }
#pragma unroll
        for (int p = 0; p < 4; ++p) {
            const int row = lrow + p * 32;
            const float4 v = *(const float4*)(Bw + (size_t)(n0 + row) * K + kc + kk);
            bl[kk + 0][row] = v.x; bl[kk + 1][row] = v.y;
            bl[kk + 2][row] = v.z; bl[kk + 3][row] = v.w;
        }
        __syncthreads();
#pragma unroll
        for (int k = 0; k < 32; ++k) {
            float av[8], bv[8];
            *(float4*)&av[0] = *(const float4*)&al[k][ty * 8];
            *(float4*)&av[4] = *(const float4*)&al[k][ty * 8 + 4];
            *(float4*)&bv[0] = *(const float4*)&bl[k][tx * 8];
            *(float4*)&bv[4] = *(const float4*)&bl[k][tx * 8 + 4];
#pragma unroll
            for (int i = 0; i < 8; ++i)
#pragma unroll
                for (int j = 0; j < 8; ++j)
                    acc[i][j] = fmaf(av[i], bv[j], acc[i][j]);
        }
    }
#pragma unroll
    for (int i = 0; i < 8; ++i) {
        const int m = m0 + ty * 8 + i;
        const size_t coff = SWC ? ((size_t)((m & 31) * T_ + (m >> 5)) * N)
                                : ((size_t)m * N);
        const float4 v0 = make_float4(acc[i][0], acc[i][1], acc[i][2], acc[i][3]);
        const float4 v1 = make_float4(acc[i][4], acc[i][5], acc[i][6], acc[i][7]);
        *(float4*)(C + coff + n0 + tx * 8) = v0;
        *(float4*)(C + coff + n0 + tx * 8 + 4) = v1;
    }
}

// ---------------------------------------------------------------------------
// K2: a_coef[t][h] = 1 - DT / softplus(tc[h] + 0.1 * mean_b |sensory[t][b][h]|)
// ---------------------------------------------------------------------------
__global__ __launch_bounds__(512) void tau_kernel(const float* __restrict__ sens,
                                                  const float* __restrict__ tc,
                                                  float* __restrict__ acoef) {
    const int t = blockIdx.x;
    const int h = threadIdx.x;
    float s = 0.f;
#pragma unroll 8
    for (int b = 0; b < B_; ++b)
        s += fabsf(sens[((size_t)t * B_ + b) * H_ + h]);
    const float x = tc[h] + 0.1f * (s * (1.f / 32.f));
    const float sp = fmaxf(x, 0.f) + log1pf(expf(-fabsf(x)));  // stable softplus
    acoef[(size_t)t * H_ + h] = 1.f - DT_ / sp;
}

// ---------------------------------------------------------------------------
// K3: the serial scan. One workgroup per batch element (32 WGs, 512 threads).
// W_r held as f16 on-CU: 12 col-groups in VGPRs + 4 col-groups in LDS.
// Thread (c, rg): rows rg*4..+3, cols c*128..+127; dot2 accumulation in fp32.
// 4-way cross-chunk reduction via LDS; h kept fp32 in regs (1 row/thread),
// re-quantized to f16 in LDS each step. Hidden states overwrite sensory
// buffer in place; out_t GEMM deferred to K4.
// ---------------------------------------------------------------------------
#define RG_ 12   // register col-groups (4 half2 each) per row
#define LG_ 4    // LDS col-groups per row
#define SMEM_W   131072                    // LG_*4*512*4 half2 * 4B
#define SMEM_P   8192                      // pred [4][512] f32
#define SMEM_H   1024                      // h2 [256] half2
#define SMEM_TOT (SMEM_W + SMEM_P + SMEM_H)

__global__ __launch_bounds__(512, 2) void scan_kernel(
    const float* __restrict__ Wr, const float* __restrict__ acoef,
    const float* __restrict__ bias, float* sensH, float* __restrict__ finalh) {
    extern __shared__ char smem[];
    half2_t* wlds = (half2_t*)smem;                        // [LG_*4][512][4]
    float* pred   = (float*)(smem + SMEM_W);               // [4][512]
    _Float16* h2s = (_Float16*)(smem + SMEM_W + SMEM_P);   // [512]

    const int tid = threadIdx.x;
    const int b = blockIdx.x;
    const int w = tid >> 6;
    const int c = w >> 1;                        // col chunk 0..3
    const int rg = ((w & 1) << 6) | (tid & 63);  // row group 0..127
    const int row0 = rg * 4;
    const int col0 = c * 128;

    // --- one-time: load + convert this thread's W_r slice ---
    half2_t wr[4][RG_ * 4];
#pragma unroll
    for (int r = 0; r < 4; ++r) {
        const float* wrow = Wr + (size_t)(row0 + r) * H_ + col0;
#pragma unroll
        for (int d = 0; d < RG_ * 4; ++d) {
            const float2 v = *(const float2*)(wrow + 2 * d);
            wr[r][d] = cvt2(v.x, v.y);
        }
#pragma unroll
        for (int g = 0; g < LG_; ++g) {
#pragma unroll
            for (int j = 0; j < 4; ++j) {
                const float2 v = *(const float2*)(wrow + 2 * ((RG_ + g) * 4 + j));
                wlds[((size_t)(g * 4 + r) * 512 + tid) * 4 + j] = cvt2(v.x, v.y);
            }
        }
    }

    if (tid < 256) ((half2_t*)h2s)[tid] = cvt2(0.f, 0.f);
    float h_reg = 0.f;
    const float bias_r = bias[tid];
    float s_cur = sensH[(size_t)b * H_ + tid];          // sensory[t=0][b][tid]
    float a_cur = acoef[tid];
    __syncthreads();

    const half2_t* h2c = (const half2_t*)h2s + c * 64;

    for (int t = 0; t < T_; ++t) {
        const int tn = (t < T_ - 1) ? t + 1 : t;
        // prefetch next step's sensory/a (consumed after the barrier below)
        const float s_nxt = sensH[((size_t)tn * B_ + b) * H_ + tid];
        const float a_nxt = acoef[(size_t)tn * H_ + tid];

        float acc[4] = {0.f, 0.f, 0.f, 0.f};
#pragma unroll
        for (int g = 0; g < RG_; ++g) {
            const float4 hv = *(const float4*)(h2c + g * 4);
            const half2_t hh[4] = {as_h2(hv.x), as_h2(hv.y), as_h2(hv.z), as_h2(hv.w)};
#pragma unroll
            for (int r = 0; r < 4; ++r)
#pragma unroll
                for (int j = 0; j < 4; ++j)
                    acc[r] = fdot2(wr[r][g * 4 + j], hh[j], acc[r]);
        }
#pragma unroll
        for (int g = 0; g < LG_; ++g) {
            const float4 hv = *(const float4*)(h2c + (RG_ + g) * 4);
            const half2_t hh[4] = {as_h2(hv.x), as_h2(hv.y), as_h2(hv.z), as_h2(hv.w)};
#pragma unroll
            for (int r = 0; r < 4; ++r) {
                const float4 wv = *(const float4*)(wlds + ((size_t)(g * 4 + r) * 512 + tid) * 4);
                acc[r] = fdot2(as_h2(wv.x), hh[0], acc[r]);
                acc[r] = fdot2(as_h2(wv.y), hh[1], acc[r]);
                acc[r] = fdot2(as_h2(wv.z), hh[2], acc[r]);
                acc[r] = fdot2(as_h2(wv.w), hh[3], acc[r]);
            }
        }
        *(float4*)(pred + c * 512 + row0) = make_float4(acc[0], acc[1], acc[2], acc[3]);
        __syncthreads();

        // update phase: thread owns h[tid]
        const float rec = pred[tid] + pred[512 + tid] + pred[1024 + tid] + pred[1536 + tid];
        const float act = tanhf(s_cur + rec + bias_r);
        h_reg = a_cur * h_reg + DT_ * act;
        sensH[((size_t)t * B_ + b) * H_ + tid] = h_reg;   // hiddens overwrite sensory
        h2s[tid] = (_Float16)h_reg;
        s_cur = s_nxt;
        a_cur = a_nxt;
        __syncthreads();
    }
    finalh[(size_t)b * H_ + tid] = h_reg;
}

// ---------------------------------------------------------------------------
extern "C" void kernel_launch(void* const* d_in, const int* in_sizes, int n_in,
                              void* d_out, int out_size, void* d_ws, size_t ws_size,
                              hipStream_t stream) {
    const float* x    = (const float*)d_in[0];
    const float* Win  = (const float*)d_in[1];
    const float* Wr   = (const float*)d_in[2];
    const float* tc   = (const float*)d_in[3];
    const float* Wo   = (const float*)d_in[4];
    const float* bias = (const float*)d_in[5];
    float* out = (float*)d_out;

    float* sensH = (float*)d_ws;                               // [T*B][H], later hiddens
    float* acoef = sensH + (size_t)T_ * B_ * H_;               // [T][H]
    const size_t need = ((size_t)T_ * B_ * H_ + (size_t)T_ * H_) * sizeof(float);
    if (ws_size < need) return;  // workspace too small -> fail loudly via validation

    (void)hipFuncSetAttribute((const void*)scan_kernel,
                              hipFuncAttributeMaxDynamicSharedMemorySize, SMEM_TOT);

    // K1: sensory[t*32+b][h] = sum_i x[b][t][i] * Win[h][i]
    {
        dim3 grid(32768 / 128, H_ / 128);
        hipLaunchKernelGGL((gemm128<H_, IN_, true, false>), grid, dim3(256), 0, stream,
                           x, Win, sensH);
    }
    // K2: a_coef
    hipLaunchKernelGGL(tau_kernel, dim3(T_), dim3(H_), 0, stream, sensH, tc, acoef);
    // K3: scan (writes hiddens into sensH, final hidden into d_out tail)
    hipLaunchKernelGGL(scan_kernel, dim3(B_), dim3(512), SMEM_TOT, stream,
                       Wr, acoef, bias, sensH, out + (size_t)B_ * T_ * O_);
    // K4: out[b][t][o] = sum_h hiddens[t*32+b][h] * Wo[o][h]
    {
        dim3 grid(32768 / 128, O_ / 128);
        hipLaunchKernelGGL((gemm128<O_, H_, false, true>), grid, dim3(256), 0, stream,
                           sensH, Wo, out);
    }
}